// Round 8
// baseline (286.971 us; speedup 1.0000x reference)
//
#include <hip/hip_runtime.h>
#include <math.h>

#define NB 16
#define NC 8
#define HH 512
#define WW 512
#define HW (HH * WW)
#define CHW (NC * HW)

#define LOG2E 1.44269504088896f
#define LN2   0.693147180559945f
#define CLMP  144.269504088896f   /* 100 * log2(e): clamp in log2 units */

typedef float f32x4 __attribute__((ext_vector_type(4)));

__device__ __forceinline__ float sigf(float x) {
    return __builtin_amdgcn_rcpf(1.0f + __builtin_amdgcn_exp2f(-x * LOG2E));
}

// Volatile asm loads: strictly ordered among themselves; compiler emits no
// waitcnt for them (we own vmcnt). "=&v" early-clobber: dest must not alias
// the address pair.
__device__ __forceinline__ f32x4 gl4(const float* p) {
    f32x4 r;
    asm volatile("global_load_dwordx4 %0, %1, off" : "=&v"(r) : "v"(p));
    return r;
}
__device__ __forceinline__ float gl1(const float* p) {
    float r;
    asm volatile("global_load_dword %0, %1, off" : "=&v"(r) : "v"(p));
    return r;
}
// First-reader pass-through. R7 failed (absmax 3e7) with sched_barrier
// fencing: RA copies / post-sched consumers still read in-flight load dests
// before the drain. Fix by DATAFLOW: the pass is a volatile asm (ordered
// after the waitcnt asm); every consumer depends on its output, so nothing
// can read a load dest pre-drain. ~98 v_movs ~= 1us total, noise.
__device__ __forceinline__ float pf(float v) {
    float r;
    asm volatile("v_mov_b32 %0, %1" : "=v"(r) : "v"(v));
    return r;
}

// R8: force all 29 loads per thread to be in flight simultaneously (one
// latency round-trip per wave instead of ~10 JIT batches). R2-R6 evidence:
// source hoist, sched_barrier, and keep-alives were all undone by the
// register-pressure scheduler (VGPR pinned at 60, dur ~105us, VALU 28%,
// HBM 20%, warm-cache identical -> pure latency bound).
__global__ __launch_bounds__(256, 2) void bicon_loss_kernel(
    const float* __restrict__ c_map,
    const float* __restrict__ target,
    const float* __restrict__ con_target,
    float* __restrict__ out)
{
    const int tid  = threadIdx.x;
    const int lane = tid & 63;
    const int wave = tid >> 6;
    const int t    = blockIdx.x * 256 + tid;
    const int g    = t >> 7;          // global row id: 0 .. 16*512-1
    const int b    = g >> 9;
    const int row  = g & 511;
    const int px0  = (t & 127) << 2;  // 0..508, contiguous within a wave

    const bool hu = row > 0, hd = row < HH - 1;
    const bool wl = px0 > 0, wr = px0 < WW - 4;
    const int rU = hu ? row - 1 : 0;      // clamped; values gated at use
    const int rD = hd ? row + 1 : HH - 1;
    const int xl = wl ? px0 - 1 : px0;
    const int xr = wr ? px0 + 4 : px0;

    const float* base = c_map + b * CHW;
    const int ro = row * WW + px0;
    const float* cm = base + ro;
    const float* ct = con_target + b * CHW + ro;

    // ====== load phase: 29 volatile asm loads, issued back-to-back ======
    f32x4 CV[8], TF[8];
    #pragma unroll
    for (int c = 0; c < 8; ++c) CV[c] = gl4(cm + c * HW);
    #pragma unroll
    for (int c = 0; c < 8; ++c) TF[c] = gl4(ct + c * HW);

    f32x4 U5 = gl4(base + 5 * HW + rU * WW + px0);
    f32x4 U6 = gl4(base + 6 * HW + rU * WW + px0);
    f32x4 U7 = gl4(base + 7 * HW + rU * WW + px0);
    f32x4 D0 = gl4(base + 0 * HW + rD * WW + px0);
    f32x4 D1 = gl4(base + 1 * HW + rD * WW + px0);
    f32x4 D2 = gl4(base + 2 * HW + rD * WW + px0);
    f32x4 TG = gl4(target + b * HW + ro);

    float e_u7p = gl1(base + 7 * HW + rU  * WW + xl);
    float e_d0p = gl1(base + 0 * HW + rD  * WW + xl);
    float e_m4p = gl1(base + 4 * HW + row * WW + xl);
    float e_u5n = gl1(base + 5 * HW + rU  * WW + xr);
    float e_d2n = gl1(base + 2 * HW + rD  * WW + xr);
    float e_m3n = gl1(base + 3 * HW + row * WW + xr);

    // single drain; all 29 results architecturally visible after this
    asm volatile("s_waitcnt vmcnt(0)" ::: "memory");
    __builtin_amdgcn_sched_barrier(0);

    // ---- first-reader pass-throughs (data edges, ordered post-drain) ----
    float cv[8][4], tvf[8][4];
    #pragma unroll
    for (int c = 0; c < 8; ++c) {
        #pragma unroll
        for (int j = 0; j < 4; ++j) { cv[c][j] = pf(CV[c][j]); tvf[c][j] = pf(TF[c][j]); }
    }
    float u5r[4], u6r[4], u7r[4], d0r[4], d1r[4], d2r[4], tg[4];
    #pragma unroll
    for (int j = 0; j < 4; ++j) {
        u5r[j] = pf(U5[j]); u6r[j] = pf(U6[j]); u7r[j] = pf(U7[j]);
        d0r[j] = pf(D0[j]); d1r[j] = pf(D1[j]); d2r[j] = pf(D2[j]);
        tg[j]  = pf(TG[j]);
    }
    const float u7p_r = pf(e_u7p);
    const float d0p_r = pf(e_d0p);
    const float m4p_r = pf(e_m4p);
    const float u5n_r = pf(e_u5n);
    const float d2n_r = pf(e_d2n);
    const float m3n_r = pf(e_m3n);

    // ================= compute phase (verbatim R6, harness-verified) ====
    //   -log2 p = log2(1+e), -log2(1-p) = c*log2e + log2(1+e), e = 2^(-c*log2e)
    float sp[8][4];
    int msk[4] = {0, 0, 0, 0};
    float acc_con = 0.0f;                       // log2 units
    #pragma unroll
    for (int c = 0; c < 8; ++c) {
        #pragma unroll
        for (int j = 0; j < 4; ++j) {
            const float cl2 = cv[c][j] * LOG2E;
            const float e   = __builtin_amdgcn_exp2f(-cl2);
            const float s   = 1.0f + e;
            const float Lg  = __builtin_amdgcn_logf(s);   // -log2(p)
            sp[c][j] = __builtin_amdgcn_rcpf(s);          // p
            const bool one = tvf[c][j] > 0.5f;
            msk[j] |= (int)one << c;
            acc_con += fminf(Lg + (one ? 0.0f : cl2), CLMP);
        }
    }

    const float sp4p = sigf(m4p_r);   // p(c4[row][px0-1])
    const float sp3n = sigf(m3n_r);   // p(c3[row][px0+4])

    float acc_bi = 0.0f, acc_de = 0.0f;         // log2 units
    #pragma unroll
    for (int j = 0; j < 4; ++j) {
        const float n6  = hu ? sigf(u6r[j]) : 0.0f;
        const float n5  = (((j < 3) ? hu : (hu && wr)))
                          ? sigf((j < 3) ? u5r[j + 1] : u5n_r) : 0.0f;
        const float n7  = (((j > 0) ? hu : (hu && wl)))
                          ? sigf((j > 0) ? u7r[j - 1] : u7p_r) : 0.0f;
        const float dn1 = hd ? sigf(d1r[j]) : 0.0f;
        const float dn2 = (((j < 3) ? hd : (hd && wr)))
                          ? sigf((j < 3) ? d2r[j + 1] : d2n_r) : 0.0f;
        const float dn0 = (((j > 0) ? hd : (hd && wl)))
                          ? sigf((j > 0) ? d0r[j - 1] : d0p_r) : 0.0f;
        const float m4  = (j > 0) ? sp[4][j - 1] : (wl ? sp4p : 0.0f);
        const float m3  = (j < 3) ? sp[3][j + 1] : (wr ? sp3n : 0.0f);

        const float a1 = sp[3][j] * m4;    // c3 * shift_right(c4)
        const float a2 = sp[4][j] * m3;    // c4 * shift_left(c3)
        const float a3 = sp[1][j] * n6;    // c1 * shift_down(c6)
        const float a4 = sp[6][j] * dn1;   // c6 * shift_up(c1)
        const float a5 = sp[2][j] * n5;    // c2 * left-bottom(c5)
        const float a6 = sp[5][j] * dn2;   // c5 * right-above(c2)
        const float a7 = sp[0][j] * n7;    // c0 * right-bottom(c7)
        const float a8 = sp[7][j] * dn0;   // c7 * left-above(c0)

        const float vote[8] = { a7, a3, a5, a1, a2, a6, a4, a8 };
        const int m = msk[j];

        #pragma unroll
        for (int c = 0; c < 8; ++c) {
            const bool one = (m >> c) & 1;
            const float q = one ? vote[c] : (1.0f - vote[c]);
            acc_bi += fminf(-__builtin_amdgcn_logf(q), CLMP);
        }

        const float glo = (a1 + a2 + a3 + a4 + a5 + a6 + a7 + a8) * 0.125f;
        float mn = vote[0];
        #pragma unroll
        for (int c = 1; c < 8; ++c) mn = fminf(mn, vote[c]);

        const bool edge = (m != 0) && (m != 255);
        const float dec = edge ? (1.0f - mn) : glo;
        const float qd  = (tg[j] > 0.5f) ? dec : (1.0f - dec);
        acc_de += fminf(-__builtin_amdgcn_logf(qd), CLMP);
    }

    float local = fmaf(0.8f, acc_con, fmaf(0.2f, acc_bi, acc_de)) * LN2;

    // ---- reduction: wave64 shuffle -> 4-float LDS -> one atomic ----
    #pragma unroll
    for (int off = 32; off > 0; off >>= 1)
        local += __shfl_down(local, off, 64);

    __shared__ float wsum[4];
    if (lane == 0) wsum[wave] = local;
    __syncthreads();
    if (tid == 0)
        atomicAdd(out, (wsum[0] + wsum[1]) + (wsum[2] + wsum[3]));
}

extern "C" void kernel_launch(void* const* d_in, const int* in_sizes, int n_in,
                              void* d_out, int out_size, void* d_ws, size_t ws_size,
                              hipStream_t stream) {
    const float* c_map      = (const float*)d_in[0];
    const float* target     = (const float*)d_in[1];
    const float* con_target = (const float*)d_in[2];
    float* out = (float*)d_out;

    hipMemsetAsync(out, 0, sizeof(float), stream);

    const int blocks = NB * (HH / 2);   // 4096 blocks x 256 thr, 4 px/thread
    bicon_loss_kernel<<<blocks, 256, 0, stream>>>(c_map, target, con_target, out);
}